// Round 8
// baseline (546.675 us; speedup 1.0000x reference)
//
#include <hip/hip_runtime.h>
#include <hip/hip_fp16.h>

typedef unsigned long long u64;

#define C2X 2.8853900817779268f   // 2*log2(e)
#define LOG2E 1.4426950408889634f

// ---------------- workspace layout (bytes) ----------------
#define WYS_OFF   0u          // half [32][256][256]  WY (prescaled C2X)
#define PR_OFF    4194304u    // half [32][256][256]  P_r  = prem @ w_r
#define PREMH_OFF 8388608u    // half [32][256][256]  premise fp16
#define PR2_OFF   12582912u   // half [32][256][256]  P_r2 = prem @ (w_t@w_r)
#define HWH_OFF   16777216u   // half [128][32][256]  (h@w_h)*C2X  (2 MB)
#define WTH_OFF   18874368u   // half [256][256] w_t
#define WTR2_OFF  19005440u   // half [256][256] W_tr2 = w_t@(w_t@w_r)
#define ZP_OFF    19136512u   // u64 [2][32][8][256] tagged z-partials (1MB); W_tr f32 stash during prep
#define RCH_OFF   20185088u   // u64 [2][32][256] tagged r-chunks (128KB)
#define MEMSET_SZ 1179648u

// ---------------- LDS layout (bytes) ----------------
#define PRC_OFF    0u        // [256][32]h P_r        (all mats XOR-swizzled)
#define WYC_OFF    16384u    // [256][32]h WY
#define PREMC_OFF  32768u    // [256][32]h prem
#define WTC_OFF    49152u    // [256][32]h w_t
#define PR2C_OFF   65536u    // [256][32]h P_r2
#define WTR2C_OFF  81920u    // [256][32]h W_tr2
#define HWHC_OFF   98304u    // [128][32]h (8 KB)
#define SCH_OFF    106496u   // 32 f32
#define WACH_OFF   106624u   // 32 f32 (prescaled -2*LOG2E)
#define RED_OFF    106752u   // [2][4] f32
#define LBUF_OFF   106784u   // 32 f32  L_t
#define AL_OFF     106912u   // [2][256] f32 e (unnormalized)
#define RB_OFF     108960u   // 256 f32 r_{t-2}
#define PART0_OFF  109984u   // [32][34] f32
#define PART1_OFF  114336u   // [32][34] f32
#define LDS_TOTAL  118688u   // >80KB => 1 block/CU => all 256 co-resident

__device__ __forceinline__ unsigned swz(unsigned o) { return o ^ ((o >> 3) & 64u); }

// ---------------- prep stage A ----------------
// blk<1024: fused WY(+C2X) & P_r rows (b,l); 1024-1535: hwh half; 1536-1567: W_tr f32 stash;
// 1568+: cvt premise (2048 blk) + w_t (64 blk). grid 3680
__global__ __launch_bounds__(256) void prep_a(const float* __restrict__ x,
                                              const float* __restrict__ wy,
                                              const float* __restrict__ wh,
                                              const float* __restrict__ wr,
                                              const float* __restrict__ wt,
                                              __half* __restrict__ wys,
                                              __half* __restrict__ prh,
                                              __half* __restrict__ hwhh,
                                              float* __restrict__ wtrf,
                                              __half* __restrict__ premh,
                                              __half* __restrict__ wth) {
    const int blk = blockIdx.x;
    if (blk >= 1568) {
        int i = (blk - 1568) * 256 + threadIdx.x;
        float4 v; __half* dst; int e;
        if (i < 524288) {
            e = i * 4; int b = e >> 16;
            v = *(const float4*)(x + (size_t)e + (size_t)b * 32768);
            dst = premh + e;
        } else if (i < 540672) {
            e = (i - 524288) * 4;
            v = *(const float4*)(wt + e);
            dst = wth + e;
        } else return;
        __half h[4] = {__float2half(v.x),__float2half(v.y),__float2half(v.z),__float2half(v.w)};
        *(uint2*)dst = *(const uint2*)h;
        return;
    }
    __shared__ float At[8][256];
    const int d = threadIdx.x;
    int mode, row0;
    if (blk < 1024)      { mode = 0; row0 = blk * 8; }
    else if (blk < 1536) { mode = 1; row0 = (blk - 1024) * 8; }
    else                 { mode = 2; row0 = (blk - 1536) * 8; }
    for (int rr = 0; rr < 8; ++rr) {
        int r = row0 + rr;
        const float* src;
        if (mode == 0)      { int b = r >> 8, l = r & 255; src = x + (size_t)(b * 384 + l) * 256; }
        else if (mode == 1) { int tt = r >> 5, bb = r & 31; src = x + (size_t)(bb * 384 + 256 + tt) * 256; }
        else                { src = wt + (size_t)r * 256; }
        At[rr][d] = src[d];
    }
    __syncthreads();
    if (mode == 0) {
        float accy[8] = {0,0,0,0,0,0,0,0}, accr[8] = {0,0,0,0,0,0,0,0};
        for (int k = 0; k < 256; k += 2) {
            float y0 = wy[(size_t)k * 256 + d], y1 = wy[(size_t)(k + 1) * 256 + d];
            float r0 = wr[(size_t)k * 256 + d], r1 = wr[(size_t)(k + 1) * 256 + d];
#pragma unroll
            for (int rr = 0; rr < 8; ++rr) {
                float2 a = *(const float2*)&At[rr][k];
                accy[rr] = fmaf(a.x, y0, accy[rr]); accy[rr] = fmaf(a.y, y1, accy[rr]);
                accr[rr] = fmaf(a.x, r0, accr[rr]); accr[rr] = fmaf(a.y, r1, accr[rr]);
            }
        }
        for (int rr = 0; rr < 8; ++rr) {
            int r = row0 + rr;
            wys[(size_t)r * 256 + d] = __float2half(accy[rr] * C2X);
            prh[(size_t)r * 256 + d] = __float2half(accr[rr]);
        }
    } else {
        const float* w = (mode == 1) ? wh : wr;
        float acc[8] = {0,0,0,0,0,0,0,0};
        for (int k = 0; k < 256; k += 4) {
            float w0 = w[(size_t)k * 256 + d], w1 = w[(size_t)(k+1) * 256 + d];
            float w2 = w[(size_t)(k+2) * 256 + d], w3 = w[(size_t)(k+3) * 256 + d];
#pragma unroll
            for (int rr = 0; rr < 8; ++rr) {
                float4 a = *(const float4*)&At[rr][k];
                float t0 = fmaf(a.x, w0, acc[rr]);
                t0 = fmaf(a.y, w1, t0);
                t0 = fmaf(a.z, w2, t0);
                acc[rr] = fmaf(a.w, w3, t0);
            }
        }
        for (int rr = 0; rr < 8; ++rr) {
            int r = row0 + rr;
            if (mode == 1) hwhh[(size_t)r * 256 + d] = __float2half(acc[rr] * C2X);
            else           wtrf[(size_t)r * 256 + d] = acc[rr];
        }
    }
}

// ---------------- prep stage B: P_r2 = prem@W_tr (1024 blk), W_tr2 = w_t@W_tr (32 blk) ----------------
__global__ __launch_bounds__(256) void prep_b(const float* __restrict__ x,
                                              const float* __restrict__ wt,
                                              const float* __restrict__ wtrf,
                                              __half* __restrict__ pr2h,
                                              __half* __restrict__ wtr2h) {
    __shared__ float At[8][256];
    const int d = threadIdx.x;
    const int blk = blockIdx.x;
    const int isP = blk < 1024;
    const int row0 = isP ? blk * 8 : (blk - 1024) * 8;
    for (int rr = 0; rr < 8; ++rr) {
        int r = row0 + rr;
        const float* src;
        if (isP) { int b = r >> 8, l = r & 255; src = x + (size_t)(b * 384 + l) * 256; }
        else     { src = wt + (size_t)r * 256; }
        At[rr][d] = src[d];
    }
    __syncthreads();
    float acc[8] = {0,0,0,0,0,0,0,0};
    for (int k = 0; k < 256; k += 4) {
        float w0 = wtrf[(size_t)k * 256 + d], w1 = wtrf[(size_t)(k+1) * 256 + d];
        float w2 = wtrf[(size_t)(k+2) * 256 + d], w3 = wtrf[(size_t)(k+3) * 256 + d];
#pragma unroll
        for (int rr = 0; rr < 8; ++rr) {
            float4 a = *(const float4*)&At[rr][k];
            float t0 = fmaf(a.x, w0, acc[rr]);
            t0 = fmaf(a.y, w1, t0);
            t0 = fmaf(a.z, w2, t0);
            acc[rr] = fmaf(a.w, w3, t0);
        }
    }
    for (int rr = 0; rr < 8; ++rr) {
        int r = row0 + rr;
        if (isP) pr2h[(size_t)r * 256 + d]  = __float2half(acc[rr]);
        else     wtr2h[(size_t)r * 256 + d] = __float2half(acc[rr]);
    }
}

// ---------------- agent-scope helpers ----------------
__device__ __forceinline__ u64 agent_load64(const u64* p) {
    return __hip_atomic_load(p, __ATOMIC_RELAXED, __HIP_MEMORY_SCOPE_AGENT);
}
__device__ __forceinline__ void agent_store64(u64* p, u64 v) {
    __hip_atomic_store(p, v, __ATOMIC_RELAXED, __HIP_MEMORY_SCOPE_AGENT);
}

// ---------------- main ----------------
__global__ __launch_bounds__(512, 1) void wbw_main(
    const __half* __restrict__ wys, const __half* __restrict__ prh,
    const __half* __restrict__ premh, const __half* __restrict__ wth,
    const __half* __restrict__ pr2h, const __half* __restrict__ wtr2h,
    const __half* __restrict__ hwhh, const float* __restrict__ walpha,
    float* __restrict__ out, u64* __restrict__ zp, u64* __restrict__ rch)
{
    extern __shared__ char lds[];
    const int tid = threadIdx.x;
    const int b = blockIdx.x >> 3, j = blockIdx.x & 7;

    float* s_ch  = (float*)(lds + SCH_OFF);
    float* wa_ch = (float*)(lds + WACH_OFF);
    float* redb  = (float*)(lds + RED_OFF);
    float* Lb    = (float*)(lds + LBUF_OFF);
    float* alb   = (float*)(lds + AL_OFF);
    float* rbb   = (float*)(lds + RB_OFF);
    float* part0 = (float*)(lds + PART0_OFF);
    float* part1 = (float*)(lds + PART1_OFF);

    // ---- stage the six [256][32] fp16 mats (XOR-swizzled) ----
    {
        const int prt = tid & 3;
        for (int it = 0; it < 2; ++it) {
            int row = it * 128 + (tid >> 2);
            size_t g = (size_t)row * 256 + j * 32 + prt * 8;
            unsigned lo = swz((unsigned)row * 64 + (unsigned)prt * 16);
            *(uint4*)(lds + PRC_OFF   + lo) = *(const uint4*)(prh   + (size_t)b * 65536 + g);
            *(uint4*)(lds + WYC_OFF   + lo) = *(const uint4*)(wys   + (size_t)b * 65536 + g);
            *(uint4*)(lds + PREMC_OFF + lo) = *(const uint4*)(premh + (size_t)b * 65536 + g);
            *(uint4*)(lds + WTC_OFF   + lo) = *(const uint4*)(wth   + g);
            *(uint4*)(lds + PR2C_OFF  + lo) = *(const uint4*)(pr2h  + (size_t)b * 65536 + g);
            *(uint4*)(lds + WTR2C_OFF + lo) = *(const uint4*)(wtr2h + g);
        }
    }
    // ---- stage hwh chunk [128][32] half ----
    for (int it = 0; it < 2; ++it) {
        int q4 = it * 512 + tid;                 // uint2 index (4 halves)
        int tt = q4 >> 3, d4 = (q4 & 7) * 4;
        *(uint2*)(lds + HWHC_OFF + (size_t)q4 * 8) =
            *(const uint2*)(hwhh + ((size_t)tt * 32 + b) * 256 + j * 32 + d4);
    }
    if (tid < 32)  { wa_ch[tid] = walpha[j * 32 + tid] * (-2.0f * LOG2E); Lb[tid] = 0.f; }
    if (tid < 256) { alb[tid] = 0.f; alb[256 + tid] = 0.f; rbb[tid] = 0.f; }
    if (tid < 8)   redb[tid] = (tid == 0 || tid == 4) ? 1.f : 0.f;
    __syncthreads();

    for (int t = 0; t <= 128; ++t) {
        const int par = t & 1, q = par ^ 1;
        const float* e1 = alb + q * 256;         // e_{t-1}
        if (t < 128) {
            // ---- A (on-chain): g1 = e_{t-1} @ P_r ----
            {
                const int seg = tid >> 4, dp = tid & 15;
                float ax = 0.f, ay = 0.f;
#pragma unroll
                for (int i = 0; i < 8; ++i) {
                    int l = seg * 8 + i;
                    float e = e1[l];
                    float2 mf = __half22float2(*(const __half2*)(lds + PRC_OFF + swz((unsigned)l * 64 + (unsigned)dp * 4)));
                    ax = fmaf(e, mf.x, ax); ay = fmaf(e, mf.y, ay);
                }
                *(float2*)&part0[seg * 34 + dp * 2] = make_float2(ax, ay);
            }
            __syncthreads();
            // ---- B: s_ch = hwh + C2X*(se*rD + L) ----
            if (tid < 32) {
                const float* rd = redb + q * 4;
                float rD = __builtin_amdgcn_rcpf(rd[0] + rd[1] + rd[2] + rd[3]);
                float se = 0.f;
#pragma unroll
                for (int s = 0; s < 32; ++s) se += part0[s * 34 + tid];
                float sv = fmaf(se, rD, Lb[tid]);
                s_ch[tid] = fmaf(sv, C2X,
                    __half2float(*(const __half*)(lds + HWHC_OFF + (size_t)(t * 32 + tid) * 2)));
            }
            __syncthreads();
            // ---- C (on-chain): sigma + tagged publish ----
            {
                const int l = tid >> 1, dh = (tid & 1) << 4;
                union { uint4 u[2]; __half h[16]; } W;
                W.u[0] = *(const uint4*)(lds + WYC_OFF + swz((unsigned)l * 64 + (unsigned)dh * 2));
                W.u[1] = *(const uint4*)(lds + WYC_OFF + swz((unsigned)l * 64 + (unsigned)dh * 2 + 16));
                float acc = 0.f;
#pragma unroll
                for (int i = 0; i < 16; ++i) {
                    float arg = __half2float(W.h[i]) + s_ch[dh + i];
                    acc = fmaf(wa_ch[dh + i],
                               __builtin_amdgcn_rcpf(__builtin_amdgcn_exp2f(arg) + 1.f), acc);
                }
                acc += __shfl_xor(acc, 1, 64);
                if ((tid & 1) == 0) {
                    u64 pk = ((u64)(unsigned)(t + 1) << 32) | (u64)__float_as_uint(acc);
                    agent_store64(&zp[(size_t)((par * 32 + b) * 8 + j) * 256 + l], pk);
                }
            }
        }
        // ---- D (hidden): r_{t-1} = a@prem + rb@w_t ; L_{t+1} = a@P_r2 + rb@W_tr2 ----
        {
            const int seg = tid >> 4, dp = tid & 15;
            const float* rd = redb + q * 4;
            float rD = __builtin_amdgcn_rcpf(rd[0] + rd[1] + rd[2] + rd[3]);
            float rx = 0.f, ry = 0.f, lx = 0.f, ly = 0.f;
#pragma unroll
            for (int i = 0; i < 8; ++i) {
                int l = seg * 8 + i;
                float a = e1[l] * rD;
                float r = rbb[l];
                unsigned o = swz((unsigned)l * 64 + (unsigned)dp * 4);
                float2 mp = __half22float2(*(const __half2*)(lds + PREMC_OFF + o));
                float2 mt = __half22float2(*(const __half2*)(lds + WTC_OFF + o));
                rx = fmaf(a, mp.x, rx); ry = fmaf(a, mp.y, ry);
                rx = fmaf(r, mt.x, rx); ry = fmaf(r, mt.y, ry);
                if (t < 128) {
                    float2 m2 = __half22float2(*(const __half2*)(lds + PR2C_OFF + o));
                    float2 m3 = __half22float2(*(const __half2*)(lds + WTR2C_OFF + o));
                    lx = fmaf(a, m2.x, lx); ly = fmaf(a, m2.y, ly);
                    lx = fmaf(r, m3.x, lx); ly = fmaf(r, m3.y, ly);
                }
            }
            *(float2*)&part0[seg * 34 + dp * 2] = make_float2(rx, ry);
            if (t < 128) *(float2*)&part1[seg * 34 + dp * 2] = make_float2(lx, ly);
        }
        __syncthreads();
        // ---- E: wave7 reduces r/L + publishes ; waves0-3 z-poll ; waves4-7 r-poll ----
        if (tid >= 448) {
            int lane = tid - 448;
            if (lane < 32) {
                float rsum = 0.f;
#pragma unroll
                for (int s = 0; s < 32; ++s) rsum += part0[s * 34 + lane];
                if (t >= 1) out[((size_t)b * 128 + (t - 1)) * 256 + j * 32 + lane] = rsum;
                if (t < 128) {
                    u64 pk = ((u64)(unsigned)t << 32) | (u64)__float_as_uint(rsum);
                    agent_store64(&rch[(size_t)(par * 32 + b) * 256 + j * 32 + lane], pk);
                }
            } else if (t < 128) {
                int d = lane - 32;
                float ls = 0.f;
#pragma unroll
                for (int s = 0; s < 32; ++s) ls += part1[s * 34 + d];
                Lb[d] = ls;
            }
        }
        if (tid < 256 && t < 128) {
            const u64* zb = zp + (size_t)(par * 32 + b) * 2048 + tid;
            u64 v0,v1,v2,v3,v4,v5,v6,v7; int tries = 0;
            for (;;) {
                v0 = agent_load64(zb);         v1 = agent_load64(zb + 256);
                v2 = agent_load64(zb + 512);   v3 = agent_load64(zb + 768);
                v4 = agent_load64(zb + 1024);  v5 = agent_load64(zb + 1280);
                v6 = agent_load64(zb + 1536);  v7 = agent_load64(zb + 1792);
                bool ok = ((unsigned)(v0 >> 32) > (unsigned)t) & ((unsigned)(v1 >> 32) > (unsigned)t)
                        & ((unsigned)(v2 >> 32) > (unsigned)t) & ((unsigned)(v3 >> 32) > (unsigned)t)
                        & ((unsigned)(v4 >> 32) > (unsigned)t) & ((unsigned)(v5 >> 32) > (unsigned)t)
                        & ((unsigned)(v6 >> 32) > (unsigned)t) & ((unsigned)(v7 >> 32) > (unsigned)t);
                if (__all(ok)) break;
                if (++tries > 2) __builtin_amdgcn_s_sleep(1);
            }
            float zs = __uint_as_float((unsigned)v0) + __uint_as_float((unsigned)v1)
                     + __uint_as_float((unsigned)v2) + __uint_as_float((unsigned)v3)
                     + __uint_as_float((unsigned)v4) + __uint_as_float((unsigned)v5)
                     + __uint_as_float((unsigned)v6) + __uint_as_float((unsigned)v7);
            float ee = __builtin_amdgcn_exp2f(zs);       // |zs| <= ~37, fp32-safe
            float sv = ee;
#pragma unroll
            for (int off = 32; off; off >>= 1) sv += __shfl_xor(sv, off, 64);
            if ((tid & 63) == 0) redb[par * 4 + (tid >> 6)] = sv;
            alb[par * 256 + tid] = ee;                   // e_t
        }
        if (tid >= 256 && t < 128) {
            const u64* rp = &rch[(size_t)(par * 32 + b) * 256 + (tid - 256)];
            u64 rv;
            for (;;) {
                rv = agent_load64(rp);
                if (__all((unsigned)(rv >> 32) >= (unsigned)t)) break;
                __builtin_amdgcn_s_sleep(1);
            }
            rbb[tid - 256] = __uint_as_float((unsigned)rv);   // r_{t-1}
        }
        __syncthreads();
    }
}

extern "C" void kernel_launch(void* const* d_in, const int* in_sizes, int n_in,
                              void* d_out, int out_size, void* d_ws, size_t ws_size,
                              hipStream_t stream) {
    const float* x   = (const float*)d_in[0];
    const float* wy  = (const float*)d_in[1];
    const float* wh  = (const float*)d_in[2];
    const float* wr  = (const float*)d_in[3];
    const float* wal = (const float*)d_in[4];
    const float* wt  = (const float*)d_in[5];

    char* ws = (char*)d_ws;
    __half* wys    = (__half*)(ws + WYS_OFF);
    __half* prh    = (__half*)(ws + PR_OFF);
    __half* premh  = (__half*)(ws + PREMH_OFF);
    __half* pr2h   = (__half*)(ws + PR2_OFF);
    __half* hwhh   = (__half*)(ws + HWH_OFF);
    __half* wth    = (__half*)(ws + WTH_OFF);
    __half* wtr2h  = (__half*)(ws + WTR2_OFF);
    float*  wtrf   = (float*)(ws + ZP_OFF);      // stash, wiped by memset after prep_b
    u64*    zp     = (u64*)(ws + ZP_OFF);
    u64*    rch    = (u64*)(ws + RCH_OFF);

    hipFuncSetAttribute((const void*)wbw_main,
                        hipFuncAttributeMaxDynamicSharedMemorySize, (int)LDS_TOTAL);

    prep_a<<<3680, 256, 0, stream>>>(x, wy, wh, wr, wt, wys, prh, hwhh, wtrf, premh, wth);
    prep_b<<<1056, 256, 0, stream>>>(x, wt, wtrf, pr2h, wtr2h);
    hipMemsetAsync(ws + ZP_OFF, 0, MEMSET_SZ, stream);

    wbw_main<<<256, 512, LDS_TOTAL, stream>>>(wys, prh, premh, wth, pr2h, wtr2h,
                                              hwhh, wal, (float*)d_out, zp, rch);
}

// Round 9
// 497.884 us; speedup vs baseline: 1.0980x; 1.0980x over previous
//
#include <hip/hip_runtime.h>
#include <hip/hip_fp16.h>

typedef unsigned long long u64;

#define C2X 2.8853900817779268f   // 2*log2(e)
#define LOG2E 1.4426950408889634f

// ---------------- workspace layout (bytes) ----------------
#define WYS_OFF   0u          // half [32][256][256]  WY (prescaled C2X)
#define PR_OFF    4194304u    // half [32][256][256]  P_r = prem @ w_r
#define PREMH_OFF 8388608u    // half [32][256][256]  premise fp16
#define HWH_OFF   12582912u   // f32  [128][32][256]  (h@w_h)*C2X
#define WTH_OFF   16777216u   // half [256][256]      w_t
#define WTR_OFF   16908288u   // half [256][256]      W_tr = w_t @ w_r
#define ZP_OFF    17039360u   // u64 [2][32][8][256]  tagged z-partials (1MB)
#define RCH_OFF   18087936u   // u64 [2][32][256]     tagged r-chunks (128KB)
#define MEMSET_SZ 1179648u

// ---------------- LDS layout (bytes) ----------------
#define PRC_OFF    0u        // [256][32]h P_r
#define WTRC_OFF   16384u    // [256][32]h W_tr
#define PREMC_OFF  32768u    // [256][32]h prem
#define WTC_OFF    49152u    // [256][32]h w_t
#define WYC_OFF    65536u    // [256][32]h WY (prescaled)
#define HWHC_OFF   81920u    // [128][32] f32
#define SCH_OFF    98304u    // 32 f32
#define WACH_OFF   98432u    // 32 f32 (prescaled -2*LOG2E)
#define RED_OFF    98560u    // [2][4] f32 (+pad)
#define ALB_OFF    98624u    // [2][256] f32 e (unnormalized), parity dbuf
#define RBB_OFF    100672u   // 256 f32 r_{t-2}
#define PART_OFF   101696u   // [32][33] f32
#define RPART_OFF  105920u   // [4][32] f32 wave partials of r
#define CTRL_OFF   106432u   // u32 counter
#define LDS_TOTAL  106496u   // >80KB => 1 block/CU => all 256 co-resident

// ---------------- prep: everything in ONE launch (proven R7) ----------------
__global__ __launch_bounds__(256) void prep_all(const float* __restrict__ x,
                                                const float* __restrict__ wy,
                                                const float* __restrict__ wh,
                                                const float* __restrict__ wr,
                                                const float* __restrict__ wt,
                                                __half* __restrict__ wys,
                                                __half* __restrict__ prh,
                                                float* __restrict__ hwh,
                                                __half* __restrict__ wtrh,
                                                __half* __restrict__ premh,
                                                __half* __restrict__ wth) {
    const int blk = blockIdx.x;
    if (blk >= 1568) {
        int i = (blk - 1568) * 256 + threadIdx.x;   // quad index
        float4 v; __half* dst; int e;
        if (i < 524288) {
            e = i * 4; int b = e >> 16;
            v = *(const float4*)(x + (size_t)e + (size_t)b * 32768);
            dst = premh + e;
        } else if (i < 540672) {
            e = (i - 524288) * 4;
            v = *(const float4*)(wt + e);
            dst = wth + e;
        } else return;
        __half h[4] = {__float2half(v.x),__float2half(v.y),__float2half(v.z),__float2half(v.w)};
        *(uint2*)dst = *(const uint2*)h;
        return;
    }
    __shared__ float At[8][256];
    const int d = threadIdx.x;
    int mode, row0;
    if (blk < 1024)      { mode = 0; row0 = blk * 8; }
    else if (blk < 1536) { mode = 1; row0 = (blk - 1024) * 8; }
    else                 { mode = 2; row0 = (blk - 1536) * 8; }
    for (int rr = 0; rr < 8; ++rr) {
        int r = row0 + rr;
        const float* src;
        if (mode == 0)      { int b = r >> 8, l = r & 255; src = x + (size_t)(b * 384 + l) * 256; }
        else if (mode == 1) { int tt = r >> 5, bb = r & 31; src = x + (size_t)(bb * 384 + 256 + tt) * 256; }
        else                { src = wt + (size_t)r * 256; }
        At[rr][d] = src[d];
    }
    __syncthreads();
    if (mode == 0) {
        float accy[8] = {0,0,0,0,0,0,0,0}, accr[8] = {0,0,0,0,0,0,0,0};
        for (int k = 0; k < 256; k += 2) {
            float y0 = wy[(size_t)k * 256 + d], y1 = wy[(size_t)(k + 1) * 256 + d];
            float r0 = wr[(size_t)k * 256 + d], r1 = wr[(size_t)(k + 1) * 256 + d];
#pragma unroll
            for (int rr = 0; rr < 8; ++rr) {
                float2 a = *(const float2*)&At[rr][k];
                accy[rr] = fmaf(a.x, y0, accy[rr]); accy[rr] = fmaf(a.y, y1, accy[rr]);
                accr[rr] = fmaf(a.x, r0, accr[rr]); accr[rr] = fmaf(a.y, r1, accr[rr]);
            }
        }
        for (int rr = 0; rr < 8; ++rr) {
            int r = row0 + rr;
            wys[(size_t)r * 256 + d] = __float2half(accy[rr] * C2X);
            prh[(size_t)r * 256 + d] = __float2half(accr[rr]);
        }
    } else {
        const float* w = (mode == 1) ? wh : wr;
        float acc[8] = {0,0,0,0,0,0,0,0};
        for (int k = 0; k < 256; k += 4) {
            float w0 = w[(size_t)k * 256 + d], w1 = w[(size_t)(k+1) * 256 + d];
            float w2 = w[(size_t)(k+2) * 256 + d], w3 = w[(size_t)(k+3) * 256 + d];
#pragma unroll
            for (int rr = 0; rr < 8; ++rr) {
                float4 a = *(const float4*)&At[rr][k];
                float t0 = fmaf(a.x, w0, acc[rr]);
                t0 = fmaf(a.y, w1, t0);
                t0 = fmaf(a.z, w2, t0);
                acc[rr] = fmaf(a.w, w3, t0);
            }
        }
        for (int rr = 0; rr < 8; ++rr) {
            int r = row0 + rr;
            if (mode == 1) hwh[(size_t)r * 256 + d] = acc[rr] * C2X;
            else           wtrh[(size_t)r * 256 + d] = __float2half(acc[rr]);
        }
    }
}

// ---------------- agent-scope helpers ----------------
__device__ __forceinline__ u64 agent_load64(const u64* p) {
    return __hip_atomic_load(p, __ATOMIC_RELAXED, __HIP_MEMORY_SCOPE_AGENT);
}
__device__ __forceinline__ void agent_store64(u64* p, u64 v) {
    __hip_atomic_store(p, v, __ATOMIC_RELAXED, __HIP_MEMORY_SCOPE_AGENT);
}

// ---------------- main: wave-specialized poll/compute overlap ----------------
__global__ __launch_bounds__(512, 1) void wbw_main(
    const __half* __restrict__ wys, const __half* __restrict__ prh,
    const __half* __restrict__ premh, const __half* __restrict__ wth,
    const __half* __restrict__ wtrh, const float* __restrict__ hwh,
    const float* __restrict__ walpha, float* __restrict__ out,
    u64* __restrict__ zp, u64* __restrict__ rch)
{
    extern __shared__ char lds[];
    const int tid = threadIdx.x;
    const int b = blockIdx.x >> 3, j = blockIdx.x & 7;

    float* hwhc  = (float*)(lds + HWHC_OFF);
    float* s_ch  = (float*)(lds + SCH_OFF);
    float* wa_ch = (float*)(lds + WACH_OFF);
    float* redb  = (float*)(lds + RED_OFF);
    float* alb   = (float*)(lds + ALB_OFF);    // [2][256]
    float* rbb   = (float*)(lds + RBB_OFF);
    float* part  = (float*)(lds + PART_OFF);   // [32][33]
    float* rpart = (float*)(lds + RPART_OFF);  // [4][32]
    unsigned* ctrL = (unsigned*)(lds + CTRL_OFF);

    // ---- stage the five [256][32] fp16 column-chunk matrices ----
    {
        const int prt = tid & 3;
        for (int it = 0; it < 2; ++it) {
            int row = it * 128 + (tid >> 2);
            size_t g = (size_t)row * 256 + j * 32 + prt * 8;
            unsigned lo = (unsigned)row * 64 + (unsigned)prt * 16;
            *(uint4*)(lds + PRC_OFF   + lo) = *(const uint4*)(prh   + (size_t)b * 65536 + g);
            *(uint4*)(lds + WTRC_OFF  + lo) = *(const uint4*)(wtrh  + g);
            *(uint4*)(lds + PREMC_OFF + lo) = *(const uint4*)(premh + (size_t)b * 65536 + g);
            *(uint4*)(lds + WTC_OFF   + lo) = *(const uint4*)(wth   + g);
            *(uint4*)(lds + WYC_OFF   + lo) = *(const uint4*)(wys   + (size_t)b * 65536 + g);
        }
    }
    for (int it = 0; it < 8; ++it) {
        int idx = it * 512 + tid;
        int tt = idx >> 5, dd = idx & 31;
        hwhc[idx] = hwh[((size_t)tt * 32 + b) * 256 + j * 32 + dd];
    }
    if (tid < 32)  wa_ch[tid] = walpha[j * 32 + tid] * (-2.0f * LOG2E);
    if (tid < 256) { alb[tid] = 0.f; alb[256 + tid] = 0.f; rbb[tid] = 0.f; }
    if (tid < 8)   redb[tid] = (tid == 0 || tid == 4) ? 1.f : 0.f;
    if (tid == 0)  *ctrL = 0u;
    __syncthreads();

    for (int t = 0; t <= 128; ++t) {
        const int par = t & 1, q = par ^ 1;
        const float* e1 = alb + q * 256;           // e_{t-1} (raw, unnormalized)
        if (t < 128) {
            // ---- P1: s-partials. waves0-3: e@P_r ; waves4-7: rbb@W_tr ----
            {
                const int half_ = tid >> 8;
                const int s16 = (tid >> 4) & 15;
                const int d0 = (tid & 15) * 2;
                const __half* mat = (const __half*)(lds + (half_ ? WTRC_OFF : PRC_OFF));
                const float* vec = half_ ? rbb : e1;
                float ax = 0.f, ay = 0.f;
#pragma unroll
                for (int i = 0; i < 16; ++i) {
                    int l = s16 + i * 16;
                    float v = vec[l];
                    float2 mf = __half22float2(*(const __half2*)&mat[l * 32 + d0]);
                    ax = fmaf(v, mf.x, ax); ay = fmaf(v, mf.y, ay);
                }
                const int row = half_ * 16 + s16;
                part[row * 33 + d0] = ax; part[row * 33 + d0 + 1] = ay;
            }
            __syncthreads();
            // ---- B: s_ch = hwh + C2X*(se*rD + sr)  (64 threads, halved depth) ----
            if (tid < 64) {
                const int d = tid & 31, h = tid >> 5;
                float sum = 0.f;
#pragma unroll
                for (int s = 0; s < 16; ++s) sum += part[(h * 16 + s) * 33 + d];
                float other = __shfl_xor(sum, 32, 64);
                if (h == 0) {
                    const float* rd = redb + q * 4;
                    float rD = __builtin_amdgcn_rcpf(rd[0] + rd[1] + rd[2] + rd[3]);
                    float sv = fmaf(sum, rD, other);
                    s_ch[d] = fmaf(sv, C2X, hwhc[t * 32 + d]);
                }
            }
            __syncthreads();
            // ---- C: sigma + tagged z publish (all 512 threads) ----
            {
                const int l = tid >> 1, dh = (tid & 1) << 4;
                union { uint4 u[2]; __half h[16]; } W;
                W.u[0] = *(const uint4*)(lds + WYC_OFF + (unsigned)l * 64 + (unsigned)dh * 2);
                W.u[1] = *(const uint4*)(lds + WYC_OFF + (unsigned)l * 64 + (unsigned)dh * 2 + 16);
                float acc = 0.f;
#pragma unroll
                for (int i = 0; i < 16; ++i) {
                    float arg = __half2float(W.h[i]) + s_ch[dh + i];
                    acc = fmaf(wa_ch[dh + i],
                               __builtin_amdgcn_rcpf(__builtin_amdgcn_exp2f(arg) + 1.f), acc);
                }
                acc += __shfl_xor(acc, 1, 64);
                if ((tid & 1) == 0) {
                    u64 pk = ((u64)(unsigned)(t + 1) << 32) | (u64)__float_as_uint(acc);
                    agent_store64(&zp[(size_t)((par * 32 + b) * 8 + j) * 256 + l], pk);
                }
            }
        }
        // ---- E-region (no barrier since C): waves4-7 r-path ∥ waves0-3 z-path ----
        if (tid >= 256) {
            // P3: r_{t-1} = alpha_{t-1}@prem + r_{t-2}@w_t  (runs every t incl. 128)
            const int t256 = tid - 256;
            const int lane = t256 & 63;
            const int w    = t256 >> 6;            // wave 0..3 within group
            const int dp   = t256 & 15;
            const int d0   = dp * 2;
            const int l0   = (t256 >> 4) * 16;     // seg*16
            const float* rd = redb + q * 4;
            float rD = __builtin_amdgcn_rcpf(rd[0] + rd[1] + rd[2] + rd[3]);
            float ax = 0.f, ay = 0.f;
#pragma unroll
            for (int i = 0; i < 16; ++i) {
                int l = l0 + i;
                float a = e1[l] * rD;
                float r = rbb[l];
                unsigned o = (unsigned)l * 64 + (unsigned)d0 * 2;
                float2 mp = __half22float2(*(const __half2*)(lds + PREMC_OFF + o));
                float2 mt = __half22float2(*(const __half2*)(lds + WTC_OFF + o));
                ax = fmaf(a, mp.x, ax); ax = fmaf(r, mt.x, ax);
                ay = fmaf(a, mp.y, ay); ay = fmaf(r, mt.y, ay);
            }
            // in-wave butterfly over the 4 local segs
            ax += __shfl_xor(ax, 16, 64); ax += __shfl_xor(ax, 32, 64);
            ay += __shfl_xor(ay, 16, 64); ay += __shfl_xor(ay, 32, 64);
            if (lane < 16) { rpart[w * 32 + d0] = ax; rpart[w * 32 + d0 + 1] = ay; }
            __threadfence_block();
            unsigned old = 0;
            if (lane == 0) old = atomicAdd(ctrL, 1u);
            old = __shfl(old, 0, 64);
            if (old == 3u) {                        // last-arriving wave finalizes
                if (lane < 32) {
                    float rsum = rpart[lane] + rpart[32 + lane]
                               + rpart[64 + lane] + rpart[96 + lane];
                    if (t >= 1)
                        out[((size_t)b * 128 + (t - 1)) * 256 + j * 32 + lane] = rsum;
                    if (t < 128) {
                        u64 pk = ((u64)(unsigned)t << 32) | (u64)__float_as_uint(rsum);
                        agent_store64(&rch[(size_t)(par * 32 + b) * 256 + j * 32 + lane], pk);
                    }
                }
                if (lane == 0) *ctrL = 0u;
            }
            // r-poll (tag >= t); each wave re-reads exactly the rbb range it read in P3
            if (t < 128) {
                const u64* rp = &rch[(size_t)(par * 32 + b) * 256 + t256];
                u64 rv;
                for (;;) {
                    rv = agent_load64(rp);
                    if (__all((unsigned)(rv >> 32) >= (unsigned)t)) break;
                    __builtin_amdgcn_s_sleep(1);
                }
                rbb[t256] = __uint_as_float((unsigned)rv);
            }
        } else if (t < 128) {
            // z-poll (tag > t) + exp + denom partials + e_t
            const u64* zb = zp + (size_t)(par * 32 + b) * 2048 + tid;
            u64 v0,v1,v2,v3,v4,v5,v6,v7; int tries = 0;
            for (;;) {
                v0 = agent_load64(zb);         v1 = agent_load64(zb + 256);
                v2 = agent_load64(zb + 512);   v3 = agent_load64(zb + 768);
                v4 = agent_load64(zb + 1024);  v5 = agent_load64(zb + 1280);
                v6 = agent_load64(zb + 1536);  v7 = agent_load64(zb + 1792);
                bool ok = ((unsigned)(v0 >> 32) > (unsigned)t) & ((unsigned)(v1 >> 32) > (unsigned)t)
                        & ((unsigned)(v2 >> 32) > (unsigned)t) & ((unsigned)(v3 >> 32) > (unsigned)t)
                        & ((unsigned)(v4 >> 32) > (unsigned)t) & ((unsigned)(v5 >> 32) > (unsigned)t)
                        & ((unsigned)(v6 >> 32) > (unsigned)t) & ((unsigned)(v7 >> 32) > (unsigned)t);
                if (__all(ok)) break;
                if (++tries > 2) __builtin_amdgcn_s_sleep(1);
            }
            float zs = __uint_as_float((unsigned)v0) + __uint_as_float((unsigned)v1)
                     + __uint_as_float((unsigned)v2) + __uint_as_float((unsigned)v3)
                     + __uint_as_float((unsigned)v4) + __uint_as_float((unsigned)v5)
                     + __uint_as_float((unsigned)v6) + __uint_as_float((unsigned)v7);
            float ee = __builtin_amdgcn_exp2f(zs);       // |zs| <= ~37, fp32-safe
            float sv = ee;
#pragma unroll
            for (int off = 32; off; off >>= 1) sv += __shfl_xor(sv, off, 64);
            if ((tid & 63) == 0) redb[par * 4 + (tid >> 6)] = sv;
            alb[par * 256 + tid] = ee;                   // e_t
        }
        __syncthreads();
    }
}

extern "C" void kernel_launch(void* const* d_in, const int* in_sizes, int n_in,
                              void* d_out, int out_size, void* d_ws, size_t ws_size,
                              hipStream_t stream) {
    const float* x   = (const float*)d_in[0];
    const float* wy  = (const float*)d_in[1];
    const float* wh  = (const float*)d_in[2];
    const float* wr  = (const float*)d_in[3];
    const float* wal = (const float*)d_in[4];
    const float* wt  = (const float*)d_in[5];

    char* ws = (char*)d_ws;
    __half* wys    = (__half*)(ws + WYS_OFF);
    __half* prh    = (__half*)(ws + PR_OFF);
    __half* premh  = (__half*)(ws + PREMH_OFF);
    float*  hwh    = (float*)(ws + HWH_OFF);
    __half* wth    = (__half*)(ws + WTH_OFF);
    __half* wtrh   = (__half*)(ws + WTR_OFF);
    u64*    zp     = (u64*)(ws + ZP_OFF);
    u64*    rch    = (u64*)(ws + RCH_OFF);

    hipFuncSetAttribute((const void*)wbw_main,
                        hipFuncAttributeMaxDynamicSharedMemorySize, (int)LDS_TOTAL);

    // grid = 1568 GEMM blocks + 2112 cvt blocks (540672 quads / 256) = 3680
    prep_all<<<3680, 256, 0, stream>>>(x, wy, wh, wr, wt, wys, prh, hwh, wtrh, premh, wth);
    hipMemsetAsync(ws + ZP_OFF, 0, MEMSET_SZ, stream);

    wbw_main<<<256, 512, LDS_TOTAL, stream>>>(wys, prh, premh, wth, wtrh, hwh,
                                              wal, (float*)d_out, zp, rch);
}

// Round 10
// 474.722 us; speedup vs baseline: 1.1516x; 1.0488x over previous
//
#include <hip/hip_runtime.h>
#include <hip/hip_fp16.h>

typedef unsigned long long u64;

#define C2X 2.8853900817779268f   // 2*log2(e)
#define LOG2E 1.4426950408889634f

// ---------------- workspace layout (bytes) ----------------
#define WYS_OFF   0u          // half [32][256][256]  WY (prescaled C2X)
#define PR_OFF    4194304u    // half [32][256][256]  P_r = prem @ w_r
#define PREMH_OFF 8388608u    // half [32][256][256]  premise fp16
#define HWH_OFF   12582912u   // f32  [128][32][256]  (h@w_h)*C2X
#define WTH_OFF   16777216u   // half [256][256]      w_t
#define WTR_OFF   16908288u   // half [256][256]      W_tr = w_t @ w_r
#define ZP_OFF    17039360u   // u64 [2][32][8][256]  tagged z-partials (1MB)
#define RCH_OFF   18087936u   // u64 [2][32][256]     tagged r-chunks (128KB)
#define MEMSET_SZ 1179648u

// ---------------- LDS layout (bytes) ----------------
// NOTE: the four GEMV matrices are contiguous so P1 selects via sel*16384.
#define PRC_OFF    0u        // [256][32]h P_r   (sel 0)
#define WTRC_OFF   16384u    // [256][32]h W_tr  (sel 1)
#define PREMC_OFF  32768u    // [256][32]h prem  (sel 2)
#define WTC_OFF    49152u    // [256][32]h w_t   (sel 3)
#define WYC_OFF    65536u    // [256][32]h WY (prescaled)
#define HWHC_OFF   81920u    // [128][32] f32
#define SCH_OFF    98304u    // 32 f32
#define WACH_OFF   98432u    // 32 f32 (prescaled -2*LOG2E)
#define RED_OFF    98560u    // [2][4] f32 (+pad)
#define ALB_OFF    98624u    // [2][256] f32 e (unnormalized), parity dbuf
#define RBB_OFF    100672u   // 256 f32 r_{t-2}
#define PART_OFF   101696u   // [32][33] f32
#define LDS_TOTAL  105920u   // >80KB => 1 block/CU => all 256 co-resident

// ---------------- prep: everything in ONE launch (proven R7) ----------------
__global__ __launch_bounds__(256) void prep_all(const float* __restrict__ x,
                                                const float* __restrict__ wy,
                                                const float* __restrict__ wh,
                                                const float* __restrict__ wr,
                                                const float* __restrict__ wt,
                                                __half* __restrict__ wys,
                                                __half* __restrict__ prh,
                                                float* __restrict__ hwh,
                                                __half* __restrict__ wtrh,
                                                __half* __restrict__ premh,
                                                __half* __restrict__ wth) {
    const int blk = blockIdx.x;
    if (blk >= 1568) {
        int i = (blk - 1568) * 256 + threadIdx.x;   // quad index
        float4 v; __half* dst; int e;
        if (i < 524288) {
            e = i * 4; int b = e >> 16;
            v = *(const float4*)(x + (size_t)e + (size_t)b * 32768);
            dst = premh + e;
        } else if (i < 540672) {
            e = (i - 524288) * 4;
            v = *(const float4*)(wt + e);
            dst = wth + e;
        } else return;
        __half h[4] = {__float2half(v.x),__float2half(v.y),__float2half(v.z),__float2half(v.w)};
        *(uint2*)dst = *(const uint2*)h;
        return;
    }
    __shared__ float At[8][256];
    const int d = threadIdx.x;
    int mode, row0;
    if (blk < 1024)      { mode = 0; row0 = blk * 8; }
    else if (blk < 1536) { mode = 1; row0 = (blk - 1024) * 8; }
    else                 { mode = 2; row0 = (blk - 1536) * 8; }
    for (int rr = 0; rr < 8; ++rr) {
        int r = row0 + rr;
        const float* src;
        if (mode == 0)      { int b = r >> 8, l = r & 255; src = x + (size_t)(b * 384 + l) * 256; }
        else if (mode == 1) { int tt = r >> 5, bb = r & 31; src = x + (size_t)(bb * 384 + 256 + tt) * 256; }
        else                { src = wt + (size_t)r * 256; }
        At[rr][d] = src[d];
    }
    __syncthreads();
    if (mode == 0) {
        float accy[8] = {0,0,0,0,0,0,0,0}, accr[8] = {0,0,0,0,0,0,0,0};
        for (int k = 0; k < 256; k += 2) {
            float y0 = wy[(size_t)k * 256 + d], y1 = wy[(size_t)(k + 1) * 256 + d];
            float r0 = wr[(size_t)k * 256 + d], r1 = wr[(size_t)(k + 1) * 256 + d];
#pragma unroll
            for (int rr = 0; rr < 8; ++rr) {
                float2 a = *(const float2*)&At[rr][k];
                accy[rr] = fmaf(a.x, y0, accy[rr]); accy[rr] = fmaf(a.y, y1, accy[rr]);
                accr[rr] = fmaf(a.x, r0, accr[rr]); accr[rr] = fmaf(a.y, r1, accr[rr]);
            }
        }
        for (int rr = 0; rr < 8; ++rr) {
            int r = row0 + rr;
            wys[(size_t)r * 256 + d] = __float2half(accy[rr] * C2X);
            prh[(size_t)r * 256 + d] = __float2half(accr[rr]);
        }
    } else {
        const float* w = (mode == 1) ? wh : wr;
        float acc[8] = {0,0,0,0,0,0,0,0};
        for (int k = 0; k < 256; k += 4) {
            float w0 = w[(size_t)k * 256 + d], w1 = w[(size_t)(k+1) * 256 + d];
            float w2 = w[(size_t)(k+2) * 256 + d], w3 = w[(size_t)(k+3) * 256 + d];
#pragma unroll
            for (int rr = 0; rr < 8; ++rr) {
                float4 a = *(const float4*)&At[rr][k];
                float t0 = fmaf(a.x, w0, acc[rr]);
                t0 = fmaf(a.y, w1, t0);
                t0 = fmaf(a.z, w2, t0);
                acc[rr] = fmaf(a.w, w3, t0);
            }
        }
        for (int rr = 0; rr < 8; ++rr) {
            int r = row0 + rr;
            if (mode == 1) hwh[(size_t)r * 256 + d] = acc[rr] * C2X;
            else           wtrh[(size_t)r * 256 + d] = __float2half(acc[rr]);
        }
    }
}

// ---------------- agent-scope helpers ----------------
__device__ __forceinline__ u64 agent_load64(const u64* p) {
    return __hip_atomic_load(p, __ATOMIC_RELAXED, __HIP_MEMORY_SCOPE_AGENT);
}
__device__ __forceinline__ void agent_store64(u64* p, u64 v) {
    __hip_atomic_store(p, v, __ATOMIC_RELAXED, __HIP_MEMORY_SCOPE_AGENT);
}

// ---------------- main: early-r-publish, split-poll pipeline ----------------
__global__ __launch_bounds__(512, 1) void wbw_main(
    const __half* __restrict__ wys, const __half* __restrict__ prh,
    const __half* __restrict__ premh, const __half* __restrict__ wth,
    const __half* __restrict__ wtrh, const float* __restrict__ hwh,
    const float* __restrict__ walpha, float* __restrict__ out,
    u64* __restrict__ zp, u64* __restrict__ rch)
{
    extern __shared__ char lds[];
    const int tid = threadIdx.x;
    const int b = blockIdx.x >> 3, j = blockIdx.x & 7;

    float* hwhc  = (float*)(lds + HWHC_OFF);
    float* s_ch  = (float*)(lds + SCH_OFF);
    float* wa_ch = (float*)(lds + WACH_OFF);
    float* redb  = (float*)(lds + RED_OFF);
    float* alb   = (float*)(lds + ALB_OFF);    // [2][256] e, parity dbuf
    float* rbb   = (float*)(lds + RBB_OFF);    // r_{t-2}
    float* part  = (float*)(lds + PART_OFF);   // [32][33]

    // ---- stage the five [256][32] fp16 column-chunk matrices ----
    {
        const int prt = tid & 3;
        for (int it = 0; it < 2; ++it) {
            int row = it * 128 + (tid >> 2);
            size_t g = (size_t)row * 256 + j * 32 + prt * 8;
            unsigned lo = (unsigned)row * 64 + (unsigned)prt * 16;
            *(uint4*)(lds + PRC_OFF   + lo) = *(const uint4*)(prh   + (size_t)b * 65536 + g);
            *(uint4*)(lds + WTRC_OFF  + lo) = *(const uint4*)(wtrh  + g);
            *(uint4*)(lds + PREMC_OFF + lo) = *(const uint4*)(premh + (size_t)b * 65536 + g);
            *(uint4*)(lds + WTC_OFF   + lo) = *(const uint4*)(wth   + g);
            *(uint4*)(lds + WYC_OFF   + lo) = *(const uint4*)(wys   + (size_t)b * 65536 + g);
        }
    }
    for (int it = 0; it < 8; ++it) {
        int idx = it * 512 + tid;
        int tt = idx >> 5, dd = idx & 31;
        hwhc[idx] = hwh[((size_t)tt * 32 + b) * 256 + j * 32 + dd];
    }
    if (tid < 32)  wa_ch[tid] = walpha[j * 32 + tid] * (-2.0f * LOG2E);
    if (tid < 256) { alb[tid] = 0.f; alb[256 + tid] = 0.f; rbb[tid] = 0.f; }
    if (tid < 8)   redb[tid] = (tid == 0 || tid == 4) ? 1.f : 0.f;
    __syncthreads();

    for (int t = 0; t <= 128; ++t) {
        const int par = t & 1, q = par ^ 1;
        const float* e1 = alb + q * 256;           // e_{t-1} (raw, unnormalized)

        // ---- P1: all four GEMV halves in one phase ----
        // sel 0: e@P_r  1: rbb@W_tr  (s-parts)   2: e@prem  3: rbb@w_t  (r-parts)
        {
            const int sel = tid >> 7;              // 0..3 (two waves each)
            const int s8  = (tid >> 4) & 7;
            const int d0  = (tid & 15) * 2;
            const __half* mat = (const __half*)(lds + (unsigned)sel * 16384u);
            const float* vec = (sel & 1) ? rbb : e1;
            float ax = 0.f, ay = 0.f;
#pragma unroll
            for (int i = 0; i < 32; ++i) {
                int l = s8 + i * 8;                // 2-way-max LDS aliasing
                float v = vec[l];
                float2 mf = __half22float2(*(const __half2*)&mat[l * 32 + d0]);
                ax = fmaf(v, mf.x, ax); ay = fmaf(v, mf.y, ay);
            }
            const int row = tid >> 4;              // 0..31
            part[row * 33 + d0] = ax; part[row * 33 + d0 + 1] = ay;
        }
        __syncthreads();

        // ---- B (wave 0): lanes0-31 s_ch ; lanes32-63 r reduce + out + EARLY publish ----
        if (tid < 64) {
            const int d = tid & 31;
            const float* rd = redb + q * 4;
            float rD = __builtin_amdgcn_rcpf(rd[0] + rd[1] + rd[2] + rd[3]);
            if (tid < 32) {
                if (t < 128) {
                    float sa = 0.f, sb = 0.f;
#pragma unroll
                    for (int s = 0; s < 8; ++s)  sa += part[s * 33 + d];
#pragma unroll
                    for (int s = 8; s < 16; ++s) sb += part[s * 33 + d];
                    s_ch[d] = fmaf(fmaf(sa, rD, sb), C2X, hwhc[t * 32 + d]);
                }
            } else {
                float ra = 0.f, rb2 = 0.f;
#pragma unroll
                for (int s = 16; s < 24; ++s) ra  += part[s * 33 + d];
#pragma unroll
                for (int s = 24; s < 32; ++s) rb2 += part[s * 33 + d];
                float rv = fmaf(ra, rD, rb2);      // r_{t-1}[d-chunk]
                if (t >= 1) out[((size_t)b * 128 + (t - 1)) * 256 + j * 32 + d] = rv;
                if (t < 128) {
                    u64 pk = ((u64)(unsigned)t << 32) | (u64)__float_as_uint(rv);
                    agent_store64(&rch[(size_t)(par * 32 + b) * 256 + j * 32 + d], pk);
                }
            }
        }
        __syncthreads();
        if (t == 128) break;

        // ---- C: sigma + tagged z publish (all 512 threads) ----
        {
            const int l = tid >> 1, dh = (tid & 1) << 4;
            union { uint4 u[2]; __half h[16]; } W;
            W.u[0] = *(const uint4*)(lds + WYC_OFF + (unsigned)l * 64 + (unsigned)dh * 2);
            W.u[1] = *(const uint4*)(lds + WYC_OFF + (unsigned)l * 64 + (unsigned)dh * 2 + 16);
            float acc = 0.f;
#pragma unroll
            for (int i = 0; i < 16; ++i) {
                float arg = __half2float(W.h[i]) + s_ch[dh + i];
                acc = fmaf(wa_ch[dh + i],
                           __builtin_amdgcn_rcpf(__builtin_amdgcn_exp2f(arg) + 1.f), acc);
            }
            acc += __shfl_xor(acc, 1, 64);
            if ((tid & 1) == 0) {
                u64 pk = ((u64)(unsigned)(t + 1) << 32) | (u64)__float_as_uint(acc);
                agent_store64(&zp[(size_t)((par * 32 + b) * 8 + j) * 256 + l], pk);
            }
        }

        // ---- E (no barrier since C): waves0-3 z-poll+exp ; waves4-7 r-poll ----
        if (tid < 256) {
            const u64* zb = zp + (size_t)(par * 32 + b) * 2048 + tid;
            u64 v0,v1,v2,v3,v4,v5,v6,v7; int tries = 0;
            for (;;) {
                v0 = agent_load64(zb);         v1 = agent_load64(zb + 256);
                v2 = agent_load64(zb + 512);   v3 = agent_load64(zb + 768);
                v4 = agent_load64(zb + 1024);  v5 = agent_load64(zb + 1280);
                v6 = agent_load64(zb + 1536);  v7 = agent_load64(zb + 1792);
                bool ok = ((unsigned)(v0 >> 32) > (unsigned)t) & ((unsigned)(v1 >> 32) > (unsigned)t)
                        & ((unsigned)(v2 >> 32) > (unsigned)t) & ((unsigned)(v3 >> 32) > (unsigned)t)
                        & ((unsigned)(v4 >> 32) > (unsigned)t) & ((unsigned)(v5 >> 32) > (unsigned)t)
                        & ((unsigned)(v6 >> 32) > (unsigned)t) & ((unsigned)(v7 >> 32) > (unsigned)t);
                if (__all(ok)) break;
                if (++tries > 2) __builtin_amdgcn_s_sleep(1);
            }
            float zs = __uint_as_float((unsigned)v0) + __uint_as_float((unsigned)v1)
                     + __uint_as_float((unsigned)v2) + __uint_as_float((unsigned)v3)
                     + __uint_as_float((unsigned)v4) + __uint_as_float((unsigned)v5)
                     + __uint_as_float((unsigned)v6) + __uint_as_float((unsigned)v7);
            float ee = __builtin_amdgcn_exp2f(zs);       // |zs| <= ~37, fp32-safe
            float sv = ee;
#pragma unroll
            for (int off = 32; off; off >>= 1) sv += __shfl_xor(sv, off, 64);
            if ((tid & 63) == 0) redb[par * 4 + (tid >> 6)] = sv;
            alb[par * 256 + tid] = ee;                   // e_t
        } else {
            // r-poll (tag >= t): r published EARLY in B => usually already arrived
            const int t256 = tid - 256;
            const u64* rp = &rch[(size_t)(par * 32 + b) * 256 + t256];
            u64 rv;
            for (;;) {
                rv = agent_load64(rp);
                if (__all((unsigned)(rv >> 32) >= (unsigned)t)) break;
                __builtin_amdgcn_s_sleep(1);
            }
            rbb[t256] = __uint_as_float((unsigned)rv);   // r_{t-1}
        }
        __syncthreads();
    }
}

extern "C" void kernel_launch(void* const* d_in, const int* in_sizes, int n_in,
                              void* d_out, int out_size, void* d_ws, size_t ws_size,
                              hipStream_t stream) {
    const float* x   = (const float*)d_in[0];
    const float* wy  = (const float*)d_in[1];
    const float* wh  = (const float*)d_in[2];
    const float* wr  = (const float*)d_in[3];
    const float* wal = (const float*)d_in[4];
    const float* wt  = (const float*)d_in[5];

    char* ws = (char*)d_ws;
    __half* wys    = (__half*)(ws + WYS_OFF);
    __half* prh    = (__half*)(ws + PR_OFF);
    __half* premh  = (__half*)(ws + PREMH_OFF);
    float*  hwh    = (float*)(ws + HWH_OFF);
    __half* wth    = (__half*)(ws + WTH_OFF);
    __half* wtrh   = (__half*)(ws + WTR_OFF);
    u64*    zp     = (u64*)(ws + ZP_OFF);
    u64*    rch    = (u64*)(ws + RCH_OFF);

    hipFuncSetAttribute((const void*)wbw_main,
                        hipFuncAttributeMaxDynamicSharedMemorySize, (int)LDS_TOTAL);

    // grid = 1568 GEMM blocks + 2112 cvt blocks (540672 quads / 256) = 3680
    prep_all<<<3680, 256, 0, stream>>>(x, wy, wh, wr, wt, wys, prh, hwh, wtrh, premh, wth);
    hipMemsetAsync(ws + ZP_OFF, 0, MEMSET_SZ, stream);

    wbw_main<<<256, 512, LDS_TOTAL, stream>>>(wys, prh, premh, wth, wtrh, hwh,
                                              wal, (float*)d_out, zp, rch);
}

// Round 11
// 447.386 us; speedup vs baseline: 1.2219x; 1.0611x over previous
//
#include <hip/hip_runtime.h>
#include <hip/hip_fp16.h>

typedef unsigned long long u64;

#define C2X 2.8853900817779268f   // 2*log2(e)
#define LOG2E 1.4426950408889634f

// ---------------- workspace layout (bytes) ----------------
#define WYS_OFF   0u          // half [32][256][256]  WY (prescaled C2X)
#define PR_OFF    4194304u    // half [32][256][256]  P_r = prem @ w_r
#define PREMH_OFF 8388608u    // half [32][256][256]  premise fp16
#define HWH_OFF   12582912u   // f32  [128][32][256]  (h@w_h)*C2X
#define WTH_OFF   16777216u   // half [256][256]      w_t
#define WTR_OFF   16908288u   // half [256][256]      W_tr = w_t @ w_r
#define ZP_OFF    17039360u   // u64 [2][32][8][256]  tagged z-partials (1MB)
#define RCH_OFF   18087936u   // u64 [2][32][256]     tagged r-chunks (128KB)
#define MEMSET_SZ 1179648u

// ---------------- LDS layout (bytes) ----------------
#define PRC_OFF    0u        // [256][32]h P_r
#define WTRC_OFF   16384u    // [256][32]h W_tr
#define PREMC_OFF  32768u    // [256][32]h prem
#define WTC_OFF    49152u    // [256][32]h w_t
#define WYC_OFF    65536u    // [256][32]h WY (prescaled)
#define HWHC_OFF   81920u    // [128][32] f32
#define SCH_OFF    98304u    // 32 f32
#define WACH_OFF   98432u    // 32 f32 (prescaled -2*LOG2E)
#define RED_OFF    98560u    // [2][4] f32 (+pad)
#define ALB_OFF    98624u    // [2][256] f32 e (unnormalized), parity dbuf
#define RBB_OFF    100672u   // 256 f32 r_{t-2}
#define PART_OFF   101696u   // [32][33] f32
#define LDS_TOTAL  105920u   // >80KB => 1 block/CU => all 256 co-resident

// ---------------- prep: everything in ONE launch (proven R7) ----------------
__global__ __launch_bounds__(256) void prep_all(const float* __restrict__ x,
                                                const float* __restrict__ wy,
                                                const float* __restrict__ wh,
                                                const float* __restrict__ wr,
                                                const float* __restrict__ wt,
                                                __half* __restrict__ wys,
                                                __half* __restrict__ prh,
                                                float* __restrict__ hwh,
                                                __half* __restrict__ wtrh,
                                                __half* __restrict__ premh,
                                                __half* __restrict__ wth) {
    const int blk = blockIdx.x;
    if (blk >= 1568) {
        int i = (blk - 1568) * 256 + threadIdx.x;   // quad index
        float4 v; __half* dst; int e;
        if (i < 524288) {
            e = i * 4; int b = e >> 16;
            v = *(const float4*)(x + (size_t)e + (size_t)b * 32768);
            dst = premh + e;
        } else if (i < 540672) {
            e = (i - 524288) * 4;
            v = *(const float4*)(wt + e);
            dst = wth + e;
        } else return;
        __half h[4] = {__float2half(v.x),__float2half(v.y),__float2half(v.z),__float2half(v.w)};
        *(uint2*)dst = *(const uint2*)h;
        return;
    }
    __shared__ float At[8][256];
    const int d = threadIdx.x;
    int mode, row0;
    if (blk < 1024)      { mode = 0; row0 = blk * 8; }
    else if (blk < 1536) { mode = 1; row0 = (blk - 1024) * 8; }
    else                 { mode = 2; row0 = (blk - 1536) * 8; }
    for (int rr = 0; rr < 8; ++rr) {
        int r = row0 + rr;
        const float* src;
        if (mode == 0)      { int b = r >> 8, l = r & 255; src = x + (size_t)(b * 384 + l) * 256; }
        else if (mode == 1) { int tt = r >> 5, bb = r & 31; src = x + (size_t)(bb * 384 + 256 + tt) * 256; }
        else                { src = wt + (size_t)r * 256; }
        At[rr][d] = src[d];
    }
    __syncthreads();
    if (mode == 0) {
        float accy[8] = {0,0,0,0,0,0,0,0}, accr[8] = {0,0,0,0,0,0,0,0};
        for (int k = 0; k < 256; k += 2) {
            float y0 = wy[(size_t)k * 256 + d], y1 = wy[(size_t)(k + 1) * 256 + d];
            float r0 = wr[(size_t)k * 256 + d], r1 = wr[(size_t)(k + 1) * 256 + d];
#pragma unroll
            for (int rr = 0; rr < 8; ++rr) {
                float2 a = *(const float2*)&At[rr][k];
                accy[rr] = fmaf(a.x, y0, accy[rr]); accy[rr] = fmaf(a.y, y1, accy[rr]);
                accr[rr] = fmaf(a.x, r0, accr[rr]); accr[rr] = fmaf(a.y, r1, accr[rr]);
            }
        }
        for (int rr = 0; rr < 8; ++rr) {
            int r = row0 + rr;
            wys[(size_t)r * 256 + d] = __float2half(accy[rr] * C2X);
            prh[(size_t)r * 256 + d] = __float2half(accr[rr]);
        }
    } else {
        const float* w = (mode == 1) ? wh : wr;
        float acc[8] = {0,0,0,0,0,0,0,0};
        for (int k = 0; k < 256; k += 4) {
            float w0 = w[(size_t)k * 256 + d], w1 = w[(size_t)(k+1) * 256 + d];
            float w2 = w[(size_t)(k+2) * 256 + d], w3 = w[(size_t)(k+3) * 256 + d];
#pragma unroll
            for (int rr = 0; rr < 8; ++rr) {
                float4 a = *(const float4*)&At[rr][k];
                float t0 = fmaf(a.x, w0, acc[rr]);
                t0 = fmaf(a.y, w1, t0);
                t0 = fmaf(a.z, w2, t0);
                acc[rr] = fmaf(a.w, w3, t0);
            }
        }
        for (int rr = 0; rr < 8; ++rr) {
            int r = row0 + rr;
            if (mode == 1) hwh[(size_t)r * 256 + d] = acc[rr] * C2X;
            else           wtrh[(size_t)r * 256 + d] = __float2half(acc[rr]);
        }
    }
}

// ---------------- agent-scope helpers ----------------
__device__ __forceinline__ u64 agent_load64(const u64* p) {
    return __hip_atomic_load(p, __ATOMIC_RELAXED, __HIP_MEMORY_SCOPE_AGENT);
}
__device__ __forceinline__ void agent_store64(u64* p, u64 v) {
    __hip_atomic_store(p, v, __ATOMIC_RELAXED, __HIP_MEMORY_SCOPE_AGENT);
}

// ---------------- main: R7 skeleton + split-poll E, LDS self-shortcut ----------------
__global__ __launch_bounds__(512, 1) void wbw_main(
    const __half* __restrict__ wys, const __half* __restrict__ prh,
    const __half* __restrict__ premh, const __half* __restrict__ wth,
    const __half* __restrict__ wtrh, const float* __restrict__ hwh,
    const float* __restrict__ walpha, float* __restrict__ out,
    u64* __restrict__ zp, u64* __restrict__ rch)
{
    extern __shared__ char lds[];
    const int tid = threadIdx.x;
    const int b = blockIdx.x >> 3, j = blockIdx.x & 7;

    float* hwhc  = (float*)(lds + HWHC_OFF);
    float* s_ch  = (float*)(lds + SCH_OFF);
    float* wa_ch = (float*)(lds + WACH_OFF);
    float* redb  = (float*)(lds + RED_OFF);
    float* alb   = (float*)(lds + ALB_OFF);    // [2][256] e, parity dbuf
    float* rbb   = (float*)(lds + RBB_OFF);    // r_{t-2}
    float* part  = (float*)(lds + PART_OFF);   // [32][33]

    // ---- stage the five [256][32] fp16 column-chunk matrices ----
    {
        const int prt = tid & 3;
        for (int it = 0; it < 2; ++it) {
            int row = it * 128 + (tid >> 2);
            size_t g = (size_t)row * 256 + j * 32 + prt * 8;
            unsigned lo = (unsigned)row * 64 + (unsigned)prt * 16;
            *(uint4*)(lds + PRC_OFF   + lo) = *(const uint4*)(prh   + (size_t)b * 65536 + g);
            *(uint4*)(lds + WTRC_OFF  + lo) = *(const uint4*)(wtrh  + g);
            *(uint4*)(lds + PREMC_OFF + lo) = *(const uint4*)(premh + (size_t)b * 65536 + g);
            *(uint4*)(lds + WTC_OFF   + lo) = *(const uint4*)(wth   + g);
            *(uint4*)(lds + WYC_OFF   + lo) = *(const uint4*)(wys   + (size_t)b * 65536 + g);
        }
    }
    for (int it = 0; it < 8; ++it) {
        int idx = it * 512 + tid;
        int tt = idx >> 5, dd = idx & 31;
        hwhc[idx] = hwh[((size_t)tt * 32 + b) * 256 + j * 32 + dd];
    }
    if (tid < 32)  wa_ch[tid] = walpha[j * 32 + tid] * (-2.0f * LOG2E);
    if (tid < 256) { alb[tid] = 0.f; alb[256 + tid] = 0.f; rbb[tid] = 0.f; }
    if (tid < 8)   redb[tid] = (tid == 0 || tid == 4) ? 1.f : 0.f;
    __syncthreads();

    for (int t = 0; t <= 128; ++t) {
        const int par = t & 1, q = par ^ 1;
        const float* e1 = alb + q * 256;           // e_{t-1} (raw, unnormalized)
        if (t < 128) {
            // ---- P1: s-partials. waves0-3: e@P_r ; waves4-7: rbb@W_tr ----
            {
                const int half_ = tid >> 8;
                const int s16 = (tid >> 4) & 15;
                const int d0 = (tid & 15) * 2;
                const __half* mat = (const __half*)(lds + (half_ ? WTRC_OFF : PRC_OFF));
                const float* vec = half_ ? rbb : e1;
                float ax = 0.f, ay = 0.f;
#pragma unroll
                for (int i = 0; i < 16; ++i) {
                    int l = s16 + i * 16;
                    float v = vec[l];
                    float2 mf = __half22float2(*(const __half2*)&mat[l * 32 + d0]);
                    ax = fmaf(v, mf.x, ax); ay = fmaf(v, mf.y, ay);
                }
                const int row = half_ * 16 + s16;
                part[row * 33 + d0] = ax; part[row * 33 + d0 + 1] = ay;
            }
            __syncthreads();
            // ---- B: s_ch = hwh + C2X*(se*rD + sr)  (64 threads, halved depth) ----
            if (tid < 64) {
                const int d = tid & 31, h = tid >> 5;
                float sum = 0.f;
#pragma unroll
                for (int s = 0; s < 16; ++s) sum += part[(h * 16 + s) * 33 + d];
                float other = __shfl_xor(sum, 32, 64);
                if (h == 0) {
                    const float* rd = redb + q * 4;
                    float rD = __builtin_amdgcn_rcpf(rd[0] + rd[1] + rd[2] + rd[3]);
                    float sv = fmaf(sum, rD, other);
                    s_ch[d] = fmaf(sv, C2X, hwhc[t * 32 + d]);
                }
            }
            __syncthreads();
            // ---- C: sigma + tagged z publish (all 512 threads) ----
            {
                const int l = tid >> 1, dh = (tid & 1) << 4;
                union { uint4 u[2]; __half h[16]; } W;
                W.u[0] = *(const uint4*)(lds + WYC_OFF + (unsigned)l * 64 + (unsigned)dh * 2);
                W.u[1] = *(const uint4*)(lds + WYC_OFF + (unsigned)l * 64 + (unsigned)dh * 2 + 16);
                float acc = 0.f;
#pragma unroll
                for (int i = 0; i < 16; ++i) {
                    float arg = __half2float(W.h[i]) + s_ch[dh + i];
                    acc = fmaf(wa_ch[dh + i],
                               __builtin_amdgcn_rcpf(__builtin_amdgcn_exp2f(arg) + 1.f), acc);
                }
                acc += __shfl_xor(acc, 1, 64);
                if ((tid & 1) == 0) {
                    u64 pk = ((u64)(unsigned)(t + 1) << 32) | (u64)__float_as_uint(acc);
                    agent_store64(&zp[(size_t)((par * 32 + b) * 8 + j) * 256 + l], pk);
                }
            }
        }
        // ---- D (after publish, off z-chain): r-partials. e@prem | rbb@w_t ----
        {
            const int half_ = tid >> 8;
            const int s16 = (tid >> 4) & 15;
            const int d0 = (tid & 15) * 2;
            const __half* mat = (const __half*)(lds + (half_ ? WTC_OFF : PREMC_OFF));
            const float* vec = half_ ? rbb : e1;   // raw e; rD applied in reduce
            float ax = 0.f, ay = 0.f;
#pragma unroll
            for (int i = 0; i < 16; ++i) {
                int l = s16 + i * 16;
                float v = vec[l];
                float2 mf = __half22float2(*(const __half2*)&mat[l * 32 + d0]);
                ax = fmaf(v, mf.x, ax); ay = fmaf(v, mf.y, ay);
            }
            const int row = half_ * 16 + s16;
            part[row * 33 + d0] = ax; part[row * 33 + d0 + 1] = ay;
        }
        __syncthreads();
        // ---- E: wave4 r-reduce+out+publish+LDS; waves4-7 r-poll ∥ waves0-3 z-poll ----
        if (tid >= 256) {
            const int t256 = tid - 256;
            if (t256 < 64) {                       // wave 4: finalize r_{t-1}
                const int d = t256 & 31, h = t256 >> 5;
                float sum = 0.f;
#pragma unroll
                for (int s = 0; s < 16; ++s) sum += part[(h * 16 + s) * 33 + d];
                float other = __shfl_xor(sum, 32, 64);
                if (h == 0) {
                    const float* rd = redb + q * 4;
                    float rD = __builtin_amdgcn_rcpf(rd[0] + rd[1] + rd[2] + rd[3]);
                    float rv = fmaf(sum, rD, other);
                    if (t >= 1) out[((size_t)b * 128 + (t - 1)) * 256 + j * 32 + d] = rv;
                    rbb[j * 32 + d] = rv;          // LDS shortcut for own chunk
                    if (t < 128) {
                        u64 pk = ((u64)(unsigned)t << 32) | (u64)__float_as_uint(rv);
                        agent_store64(&rch[(size_t)(par * 32 + b) * 256 + j * 32 + d], pk);
                    }
                }
            }
            // r-poll (tag >= t), one entry per thread; skip own chunk (LDS-fresh)
            if (t < 128 && (t256 >> 5) != j) {
                const u64* rp = &rch[(size_t)(par * 32 + b) * 256 + t256];
                u64 rv;
                for (;;) {
                    rv = agent_load64(rp);
                    if (__all((unsigned)(rv >> 32) >= (unsigned)t)) break;
                    __builtin_amdgcn_s_sleep(1);
                }
                rbb[t256] = __uint_as_float((unsigned)rv);   // r_{t-1}
            }
        } else if (t < 128) {
            // z-poll (tag > t) + exp + denom partials + e_t
            const u64* zb = zp + (size_t)(par * 32 + b) * 2048 + tid;
            u64 v0,v1,v2,v3,v4,v5,v6,v7; int tries = 0;
            for (;;) {
                v0 = agent_load64(zb);         v1 = agent_load64(zb + 256);
                v2 = agent_load64(zb + 512);   v3 = agent_load64(zb + 768);
                v4 = agent_load64(zb + 1024);  v5 = agent_load64(zb + 1280);
                v6 = agent_load64(zb + 1536);  v7 = agent_load64(zb + 1792);
                bool ok = ((unsigned)(v0 >> 32) > (unsigned)t) & ((unsigned)(v1 >> 32) > (unsigned)t)
                        & ((unsigned)(v2 >> 32) > (unsigned)t) & ((unsigned)(v3 >> 32) > (unsigned)t)
                        & ((unsigned)(v4 >> 32) > (unsigned)t) & ((unsigned)(v5 >> 32) > (unsigned)t)
                        & ((unsigned)(v6 >> 32) > (unsigned)t) & ((unsigned)(v7 >> 32) > (unsigned)t);
                if (__all(ok)) break;
                if (++tries > 2) __builtin_amdgcn_s_sleep(1);
            }
            float zs = __uint_as_float((unsigned)v0) + __uint_as_float((unsigned)v1)
                     + __uint_as_float((unsigned)v2) + __uint_as_float((unsigned)v3)
                     + __uint_as_float((unsigned)v4) + __uint_as_float((unsigned)v5)
                     + __uint_as_float((unsigned)v6) + __uint_as_float((unsigned)v7);
            float ee = __builtin_amdgcn_exp2f(zs);       // |zs| <= ~37, fp32-safe
            float sv = ee;
#pragma unroll
            for (int off = 32; off; off >>= 1) sv += __shfl_xor(sv, off, 64);
            if ((tid & 63) == 0) redb[par * 4 + (tid >> 6)] = sv;
            alb[par * 256 + tid] = ee;                   // e_t
        }
        __syncthreads();
    }
}

extern "C" void kernel_launch(void* const* d_in, const int* in_sizes, int n_in,
                              void* d_out, int out_size, void* d_ws, size_t ws_size,
                              hipStream_t stream) {
    const float* x   = (const float*)d_in[0];
    const float* wy  = (const float*)d_in[1];
    const float* wh  = (const float*)d_in[2];
    const float* wr  = (const float*)d_in[3];
    const float* wal = (const float*)d_in[4];
    const float* wt  = (const float*)d_in[5];

    char* ws = (char*)d_ws;
    __half* wys    = (__half*)(ws + WYS_OFF);
    __half* prh    = (__half*)(ws + PR_OFF);
    __half* premh  = (__half*)(ws + PREMH_OFF);
    float*  hwh    = (float*)(ws + HWH_OFF);
    __half* wth    = (__half*)(ws + WTH_OFF);
    __half* wtrh   = (__half*)(ws + WTR_OFF);
    u64*    zp     = (u64*)(ws + ZP_OFF);
    u64*    rch    = (u64*)(ws + RCH_OFF);

    hipFuncSetAttribute((const void*)wbw_main,
                        hipFuncAttributeMaxDynamicSharedMemorySize, (int)LDS_TOTAL);

    // grid = 1568 GEMM blocks + 2112 cvt blocks (540672 quads / 256) = 3680
    prep_all<<<3680, 256, 0, stream>>>(x, wy, wh, wr, wt, wys, prh, hwh, wtrh, premh, wth);
    hipMemsetAsync(ws + ZP_OFF, 0, MEMSET_SZ, stream);

    wbw_main<<<256, 512, LDS_TOTAL, stream>>>(wys, prh, premh, wth, wtrh, hwh,
                                              wal, (float*)d_out, zp, rch);
}